// Round 1
// baseline (374.602 us; speedup 1.0000x reference)
//
#include <hip/hip_runtime.h>
#include <hip/hip_bf16.h>

// lw(x) = -0.5 * (x^T Q x + x.v + c)
//   Q = I - A - A^T + 2 A A^T   (64x64, symmetric)
//   v = 4Ab - 2b - 2A theta
//   c = 2||b||^2 - 2 b.theta + ||theta||^2
// ELBO = -(1/1024) * sum_rows ( sum e^{lw-m} lw / sum e^{lw-m} ), rows = 1024 consecutive samples.

typedef __attribute__((ext_vector_type(8))) short short8;   // 8 bf16 = 4 VGPRs (MFMA A/B frag)
typedef __attribute__((ext_vector_type(4))) float floatx4;  // MFMA C/D frag

#define WS_QT 0       // ushort[4096]  : Q^T in bf16, Qt[d*64+k] = Q[k][d]
#define WS_V  8192    // float[64]
#define WS_C  8448    // float
#define WS_R  8704    // float[1024]   : per-row softmax results

__device__ __forceinline__ short bf16r(float f) {
  __hip_bfloat16 h = __float2bfloat16(f);   // RNE
  short r; __builtin_memcpy(&r, &h, 2); return r;
}

__device__ __forceinline__ short8 cvt_bf16x8(float4 a, float4 b) {
  short8 r;
  r[0]=bf16r(a.x); r[1]=bf16r(a.y); r[2]=bf16r(a.z); r[3]=bf16r(a.w);
  r[4]=bf16r(b.x); r[5]=bf16r(b.y); r[6]=bf16r(b.z); r[7]=bf16r(b.w);
  return r;
}

__global__ void prep_kernel(const float* __restrict__ A, const float* __restrict__ b,
                            const float* __restrict__ th, unsigned short* __restrict__ Qt,
                            float* __restrict__ v, float* __restrict__ cws) {
  const int k = blockIdx.x, d = threadIdx.x;   // 64 blocks x 64 threads
  float qs = 0.f;
  for (int j = 0; j < 64; ++j) qs = fmaf(A[k*64+j], A[d*64+j], qs);
  float Qkd = (k == d ? 1.f : 0.f) + 2.f*qs - A[k*64+d] - A[d*64+k];
  __hip_bfloat16 h = __float2bfloat16(Qkd);
  unsigned short u; __builtin_memcpy(&u, &h, 2);
  Qt[d*64 + k] = u;                            // transposed: consecutive k per d -> 16B frag loads
  if (k == 0) {
    float s = -2.f*b[d];
    for (int j = 0; j < 64; ++j) s = fmaf(A[d*64+j], 4.f*b[j] - 2.f*th[j], s);
    v[d] = s;
    if (d == 0) {
      float cc = 0.f;
      for (int j = 0; j < 64; ++j) cc += 2.f*b[j]*b[j] - 2.f*b[j]*th[j] + th[j]*th[j];
      *cws = cc;
    }
  }
}

// One block per softmax row (1024 samples). 256 threads = 4 waves; each wave does
// 16 tiles of 16 samples. MFMA 16x16x32 bf16: A = x tile, B = Q (resident in regs).
__global__ __launch_bounds__(256) void main_kernel(
    const float* __restrict__ x, const unsigned short* __restrict__ Qt,
    const float* __restrict__ v, const float* __restrict__ cptr,
    float* __restrict__ rbuf) {
  __shared__ __align__(16) float xlds[4][16*68];   // per-wave x staging, pad 68 -> conflict-free
  __shared__ __align__(16) float lws[1024];
  __shared__ float wredA[4], wredB[4], wredC[4];

  const int tid = threadIdx.x;
  const int w = tid >> 6, l = tid & 63, q = l >> 4, s = l & 15;
  const int n0 = blockIdx.x << 10;

  // B fragments (Q), 2 K-steps x 4 col-tiles: elem j <-> B[k=ks*32+q*8+j][n=tt*16+s]
  short8 bfrag[2][4];
  #pragma unroll
  for (int ks = 0; ks < 2; ++ks)
    #pragma unroll
    for (int tt = 0; tt < 4; ++tt)
      bfrag[ks][tt] = *(const short8*)(Qt + (tt*16 + s)*64 + ks*32 + q*8);

  float vreg[4];
  #pragma unroll
  for (int tt = 0; tt < 4; ++tt) vreg[tt] = v[tt*16 + s];
  const float cc = *cptr;

  float* xw = &xlds[w][s*68 + q*8];

  for (int t = 0; t < 16; ++t) {
    const int row0 = (w*16 + t)*16;
    const float* xp = x + ((size_t)(n0 + row0 + s))*64 + q*8;
    float4 xa = *(const float4*)(xp);
    float4 xb = *(const float4*)(xp + 4);
    float4 xc = *(const float4*)(xp + 32);
    float4 xd = *(const float4*)(xp + 36);

    // A fragments: elem j <-> A[m=s][k=q*8+j] (+32 for frag1)
    short8 af0 = cvt_bf16x8(xa, xb);
    short8 af1 = cvt_bf16x8(xc, xd);

    floatx4 acc[4];
    #pragma unroll
    for (int tt = 0; tt < 4; ++tt) {
      floatx4 z4 = {0.f, 0.f, 0.f, 0.f};
      acc[tt] = __builtin_amdgcn_mfma_f32_16x16x32_bf16(af0, bfrag[0][tt], z4, 0, 0, 0);
      acc[tt] = __builtin_amdgcn_mfma_f32_16x16x32_bf16(af1, bfrag[1][tt], acc[tt], 0, 0, 0);
    }

    // stage exact f32 x for the epilogue rowdot (wave-private region, no barrier needed)
    *(float4*)(xw)      = xa;
    *(float4*)(xw + 4)  = xb;
    *(float4*)(xw + 32) = xc;
    *(float4*)(xw + 36) = xd;

    // rowdot: lane holds y[m=q*4+r][d=tt*16+s] in acc[tt][r]
    float pl[4] = {0.f, 0.f, 0.f, 0.f};
    #pragma unroll
    for (int tt = 0; tt < 4; ++tt) {
      const float* xr = &xlds[w][(q*4)*68 + tt*16 + s];
      #pragma unroll
      for (int r = 0; r < 4; ++r)
        pl[r] = fmaf(acc[tt][r] + vreg[tt], xr[r*68], pl[r]);
    }
    // reduce over the 16 cols (lane bits 0..3), then lw = -0.5*(sum + c)
    #pragma unroll
    for (int r = 0; r < 4; ++r) {
      float p = pl[r];
      p += __shfl_xor(p, 1, 64);
      p += __shfl_xor(p, 2, 64);
      p += __shfl_xor(p, 4, 64);
      p += __shfl_xor(p, 8, 64);
      pl[r] = -0.5f * (p + cc);
    }
    if (s == 0) {
      float4 st = make_float4(pl[0], pl[1], pl[2], pl[3]);
      *(float4*)&lws[row0 + q*4] = st;   // samples row0+q*4 .. +3
    }
  }

  __syncthreads();
  // softmax-weighted mean over the block's 1024 lw values
  float4 mv = ((const float4*)lws)[tid];
  float mx = fmaxf(fmaxf(mv.x, mv.y), fmaxf(mv.z, mv.w));
  #pragma unroll
  for (int m = 1; m < 64; m <<= 1) mx = fmaxf(mx, __shfl_xor(mx, m, 64));
  if (l == 0) wredA[w] = mx;
  __syncthreads();
  const float bmax = fmaxf(fmaxf(wredA[0], wredA[1]), fmaxf(wredA[2], wredA[3]));

  float s1 = 0.f, s2 = 0.f, e;
  e = __expf(mv.x - bmax); s1 += e; s2 = fmaf(e, mv.x, s2);
  e = __expf(mv.y - bmax); s1 += e; s2 = fmaf(e, mv.y, s2);
  e = __expf(mv.z - bmax); s1 += e; s2 = fmaf(e, mv.z, s2);
  e = __expf(mv.w - bmax); s1 += e; s2 = fmaf(e, mv.w, s2);
  #pragma unroll
  for (int m = 1; m < 64; m <<= 1) {
    s1 += __shfl_xor(s1, m, 64);
    s2 += __shfl_xor(s2, m, 64);
  }
  if (l == 0) { wredB[w] = s1; wredC[w] = s2; }
  __syncthreads();
  if (tid == 0) {
    float S1 = wredB[0] + wredB[1] + wredB[2] + wredB[3];
    float S2 = wredC[0] + wredC[1] + wredC[2] + wredC[3];
    rbuf[blockIdx.x] = S2 / S1;
  }
}

__global__ void finish_kernel(const float* __restrict__ rbuf, float* __restrict__ out) {
  __shared__ float wsum[4];
  const int tid = threadIdx.x;
  float4 vv = ((const float4*)rbuf)[tid];     // 256 threads x 4 = 1024
  float s = vv.x + vv.y + vv.z + vv.w;
  #pragma unroll
  for (int m = 1; m < 64; m <<= 1) s += __shfl_xor(s, m, 64);
  if ((tid & 63) == 0) wsum[tid >> 6] = s;
  __syncthreads();
  if (tid == 0) out[0] = -(wsum[0] + wsum[1] + wsum[2] + wsum[3]) * (1.0f / 1024.0f);
}

extern "C" void kernel_launch(void* const* d_in, const int* in_sizes, int n_in,
                              void* d_out, int out_size, void* d_ws, size_t ws_size,
                              hipStream_t stream) {
  const float* x  = (const float*)d_in[0];
  const float* A  = (const float*)d_in[1];
  const float* b  = (const float*)d_in[2];
  const float* th = (const float*)d_in[3];
  char* ws = (char*)d_ws;
  unsigned short* Qt = (unsigned short*)(ws + WS_QT);
  float* v    = (float*)(ws + WS_V);
  float* cws  = (float*)(ws + WS_C);
  float* rbuf = (float*)(ws + WS_R);
  float* out  = (float*)d_out;

  prep_kernel<<<64, 64, 0, stream>>>(A, b, th, Qt, v, cws);
  main_kernel<<<1024, 256, 0, stream>>>(x, Qt, v, cws, rbuf);
  finish_kernel<<<1, 256, 0, stream>>>(rbuf, out);
}

// Round 2
// 371.387 us; speedup vs baseline: 1.0087x; 1.0087x over previous
//
#include <hip/hip_runtime.h>
#include <hip/hip_bf16.h>

// lw(x) = -0.5 * ( ||x(I-A) - b||^2 + ||xA + (b - theta)||^2 )
// i.e. G = x . U with U = [I-A | A]  (64 x 128),  column consts cvec = [-b | b-theta]
// lw = -0.5 * sum_n (G[n] + cvec[n])^2, with cvec folded into the MFMA accumulator init.
// ELBO = -(1/1024) * sum_rows softmax-weighted mean of lw over 1024 consecutive samples.

typedef __attribute__((ext_vector_type(8))) short short8;   // 8 bf16 = 4 VGPRs (MFMA A/B frag)
typedef __attribute__((ext_vector_type(4))) float floatx4;  // MFMA C/D frag

#define WS_UT 0        // ushort[128*64] : U^T bf16, Ut[n*64+k] = U[k][n]
#define WS_CV 16384    // float[128]     : column constants
#define WS_R  17920    // float[1024]    : per-softmax-row results

__device__ __forceinline__ short bf16r(float f) {
  __hip_bfloat16 h = __float2bfloat16(f);   // RNE
  short r; __builtin_memcpy(&r, &h, 2); return r;
}

__device__ __forceinline__ short8 cvt_bf16x8(float4 a, float4 b) {
  short8 r;
  r[0]=bf16r(a.x); r[1]=bf16r(a.y); r[2]=bf16r(a.z); r[3]=bf16r(a.w);
  r[4]=bf16r(b.x); r[5]=bf16r(b.y); r[6]=bf16r(b.z); r[7]=bf16r(b.w);
  return r;
}

__global__ void prep_kernel(const float* __restrict__ A, const float* __restrict__ b,
                            const float* __restrict__ th,
                            unsigned short* __restrict__ Ut, float* __restrict__ cvec) {
  const int i = blockIdx.x * 256 + threadIdx.x;   // 8192 threads: k = i>>7, n = i&127
  const int k = i >> 7, n = i & 127;
  float u;
  if (n < 64) u = (k == n ? 1.f : 0.f) - A[k*64 + n];
  else        u = A[k*64 + (n - 64)];
  __hip_bfloat16 h = __float2bfloat16(u);
  unsigned short us; __builtin_memcpy(&us, &h, 2);
  Ut[n*64 + k] = us;                               // transposed for contiguous B-frag loads
  if (i < 128) cvec[i] = (i < 64) ? -b[i] : (b[i - 64] - th[i - 64]);
}

// One block per softmax row (1024 samples). 256 threads = 4 waves; each wave does
// 16 tiles of 16 samples. MFMA 16x16x32 bf16: A = x tile, B = U (resident in regs).
__global__ __launch_bounds__(256) void main_kernel(
    const float* __restrict__ x, const unsigned short* __restrict__ Ut,
    const float* __restrict__ cvec, float* __restrict__ rbuf) {
  __shared__ __align__(16) float lws[1024];
  __shared__ float wredA[4], wredB[4], wredC[4];

  const int tid = threadIdx.x;
  const int w = tid >> 6, l = tid & 63, q = l >> 4, s = l & 15;
  const int n0 = blockIdx.x << 10;

  // B fragments (U), 2 K-steps x 8 col-tiles: elem j <-> U[k=ks*32+q*8+j][n=u*16+s]
  short8 bfrag[2][8];
  #pragma unroll
  for (int ks = 0; ks < 2; ++ks)
    #pragma unroll
    for (int u = 0; u < 8; ++u)
      bfrag[ks][u] = *(const short8*)(Ut + (u*16 + s)*64 + ks*32 + q*8);

  float cv[8];
  #pragma unroll
  for (int u = 0; u < 8; ++u) cv[u] = cvec[u*16 + s];

  // wave w streams rows [n0 + w*256, +256) as 16 tiles of 16 rows
  const float* base = x + ((size_t)(n0 + w*256 + s))*64 + q*8;

  float4 c0 = *(const float4*)(base);
  float4 c1 = *(const float4*)(base + 4);
  float4 c2 = *(const float4*)(base + 32);
  float4 c3 = *(const float4*)(base + 36);

  #pragma unroll 2
  for (int t = 0; t < 16; ++t) {
    // prefetch tile t+1 (clamped; last-iter reload hits L1)
    const float* pn = base + (size_t)((t < 15 ? t + 1 : 15)) * 1024;
    float4 p0 = *(const float4*)(pn);
    float4 p1 = *(const float4*)(pn + 4);
    float4 p2 = *(const float4*)(pn + 32);
    float4 p3 = *(const float4*)(pn + 36);

    // A fragments: elem j <-> A[m=s][k=q*8+j] (af1: k+32)
    short8 af0 = cvt_bf16x8(c0, c1);
    short8 af1 = cvt_bf16x8(c2, c3);

    float sl[4] = {0.f, 0.f, 0.f, 0.f};
    #pragma unroll
    for (int u = 0; u < 8; ++u) {
      floatx4 acc = {cv[u], cv[u], cv[u], cv[u]};   // column const folded into C init
      acc = __builtin_amdgcn_mfma_f32_16x16x32_bf16(af0, bfrag[0][u], acc, 0, 0, 0);
      acc = __builtin_amdgcn_mfma_f32_16x16x32_bf16(af1, bfrag[1][u], acc, 0, 0, 0);
      #pragma unroll
      for (int r = 0; r < 4; ++r) sl[r] = fmaf(acc[r], acc[r], sl[r]);
    }

    // reduce over the 16 cols this lane group covers (lane bits 0..3)
    #pragma unroll
    for (int r = 0; r < 4; ++r) {
      float p = sl[r];
      p += __shfl_xor(p, 1, 64);
      p += __shfl_xor(p, 2, 64);
      p += __shfl_xor(p, 4, 64);
      p += __shfl_xor(p, 8, 64);
      sl[r] = -0.5f * p;
    }
    if (s == 0) {
      const int row0 = w*256 + t*16;
      float4 st = make_float4(sl[0], sl[1], sl[2], sl[3]);
      *(float4*)&lws[row0 + q*4] = st;   // samples row0+q*4 .. +3
    }

    c0 = p0; c1 = p1; c2 = p2; c3 = p3;
  }

  __syncthreads();
  // softmax-weighted mean over the block's 1024 lw values
  float4 mv = ((const float4*)lws)[tid];
  float mx = fmaxf(fmaxf(mv.x, mv.y), fmaxf(mv.z, mv.w));
  #pragma unroll
  for (int m = 1; m < 64; m <<= 1) mx = fmaxf(mx, __shfl_xor(mx, m, 64));
  if (l == 0) wredA[w] = mx;
  __syncthreads();
  const float bmax = fmaxf(fmaxf(wredA[0], wredA[1]), fmaxf(wredA[2], wredA[3]));

  float s1 = 0.f, s2 = 0.f, e;
  e = __expf(mv.x - bmax); s1 += e; s2 = fmaf(e, mv.x, s2);
  e = __expf(mv.y - bmax); s1 += e; s2 = fmaf(e, mv.y, s2);
  e = __expf(mv.z - bmax); s1 += e; s2 = fmaf(e, mv.z, s2);
  e = __expf(mv.w - bmax); s1 += e; s2 = fmaf(e, mv.w, s2);
  #pragma unroll
  for (int m = 1; m < 64; m <<= 1) {
    s1 += __shfl_xor(s1, m, 64);
    s2 += __shfl_xor(s2, m, 64);
  }
  if (l == 0) { wredB[w] = s1; wredC[w] = s2; }
  __syncthreads();
  if (tid == 0) {
    float S1 = wredB[0] + wredB[1] + wredB[2] + wredB[3];
    float S2 = wredC[0] + wredC[1] + wredC[2] + wredC[3];
    rbuf[blockIdx.x] = S2 / S1;
  }
}

__global__ void finish_kernel(const float* __restrict__ rbuf, float* __restrict__ out) {
  __shared__ float wsum[4];
  const int tid = threadIdx.x;
  float4 vv = ((const float4*)rbuf)[tid];     // 256 threads x 4 = 1024
  float s = vv.x + vv.y + vv.z + vv.w;
  #pragma unroll
  for (int m = 1; m < 64; m <<= 1) s += __shfl_xor(s, m, 64);
  if ((tid & 63) == 0) wsum[tid >> 6] = s;
  __syncthreads();
  if (tid == 0) out[0] = -(wsum[0] + wsum[1] + wsum[2] + wsum[3]) * (1.0f / 1024.0f);
}

extern "C" void kernel_launch(void* const* d_in, const int* in_sizes, int n_in,
                              void* d_out, int out_size, void* d_ws, size_t ws_size,
                              hipStream_t stream) {
  const float* x  = (const float*)d_in[0];
  const float* A  = (const float*)d_in[1];
  const float* b  = (const float*)d_in[2];
  const float* th = (const float*)d_in[3];
  char* ws = (char*)d_ws;
  unsigned short* Ut = (unsigned short*)(ws + WS_UT);
  float* cvec = (float*)(ws + WS_CV);
  float* rbuf = (float*)(ws + WS_R);
  float* out  = (float*)d_out;

  prep_kernel<<<32, 256, 0, stream>>>(A, b, th, Ut, cvec);
  main_kernel<<<1024, 256, 0, stream>>>(x, Ut, cvec, rbuf);
  finish_kernel<<<1, 256, 0, stream>>>(rbuf, out);
}